// Round 1
// baseline (903.976 us; speedup 1.0000x reference)
//
#include <hip/hip_runtime.h>

typedef __attribute__((ext_vector_type(8))) short s8v;
typedef __attribute__((ext_vector_type(4))) float f4v;

constexpr int BN = 16;
constexpr int TQ = 2048;
constexpr int TK = 2048;
constexpr int DH = 128;

__device__ __forceinline__ unsigned short f2bf(float f) {
  unsigned int u = __float_as_uint(f);
  u += 0x7fffu + ((u >> 16) & 1u);   // round-to-nearest-even
  return (unsigned short)(u >> 16);
}
__device__ __forceinline__ float bf2f(unsigned short h) {
  return __uint_as_float(((unsigned int)h) << 16);
}

// ---------------------------------------------------------------------------
// Kernel 1: S = Q K^T / sqrt(D) + mask*(-1e4); P = exp(S) -> attn region;
//           Z[b,k] += column sums (softmax is over the q axis!).
// 128x128 tile per block, split-bf16 3-term MFMA over 32-wide d-chunks.
// ---------------------------------------------------------------------------
__global__ __launch_bounds__(256) void qk_exp_kernel(
    const float* __restrict__ Q, const float* __restrict__ K,
    const float* __restrict__ Msk, float* __restrict__ P,
    float* __restrict__ Z)
{
  __shared__ __align__(16) unsigned short qhi[128][40];
  __shared__ __align__(16) unsigned short qlo[128][40];
  __shared__ __align__(16) unsigned short khi[128][40];
  __shared__ __align__(16) unsigned short klo[128][40];

  const int kb = blockIdx.x, qb = blockIdx.y, b = blockIdx.z;
  const int tid = threadIdx.x;
  const int wave = tid >> 6, lane = tid & 63;
  const int wr = wave >> 1, wc = wave & 1;
  const int quad = lane >> 4, l16 = lane & 15;

  f4v acc[4][4];
#pragma unroll
  for (int i = 0; i < 4; ++i)
#pragma unroll
    for (int j = 0; j < 4; ++j)
      acc[i][j] = (f4v){0.f, 0.f, 0.f, 0.f};

  const float* Qb = Q + ((size_t)b * TQ + (size_t)qb * 128) * DH;
  const float* Kb = K + ((size_t)b * TK + (size_t)kb * 128) * DH;

  for (int dc = 0; dc < DH; dc += 32) {
    __syncthreads();
#pragma unroll
    for (int i = 0; i < 4; ++i) {
      int idx = i * 256 + tid;
      int r = idx >> 3, c = (idx & 7) * 4;
      float4 qv = *(const float4*)(Qb + (size_t)r * DH + dc + c);
      float4 kv = *(const float4*)(Kb + (size_t)r * DH + dc + c);
      unsigned short h;
      h = f2bf(qv.x); qhi[r][c+0] = h; qlo[r][c+0] = f2bf(qv.x - bf2f(h));
      h = f2bf(qv.y); qhi[r][c+1] = h; qlo[r][c+1] = f2bf(qv.y - bf2f(h));
      h = f2bf(qv.z); qhi[r][c+2] = h; qlo[r][c+2] = f2bf(qv.z - bf2f(h));
      h = f2bf(qv.w); qhi[r][c+3] = h; qlo[r][c+3] = f2bf(qv.w - bf2f(h));
      h = f2bf(kv.x); khi[r][c+0] = h; klo[r][c+0] = f2bf(kv.x - bf2f(h));
      h = f2bf(kv.y); khi[r][c+1] = h; klo[r][c+1] = f2bf(kv.y - bf2f(h));
      h = f2bf(kv.z); khi[r][c+2] = h; klo[r][c+2] = f2bf(kv.z - bf2f(h));
      h = f2bf(kv.w); khi[r][c+3] = h; klo[r][c+3] = f2bf(kv.w - bf2f(h));
    }
    __syncthreads();

    s8v ah[4], al[4], bh[4], bl[4];
#pragma unroll
    for (int i = 0; i < 4; ++i) {
      ah[i] = *(const s8v*)&qhi[wr*64 + i*16 + l16][quad*8];
      al[i] = *(const s8v*)&qlo[wr*64 + i*16 + l16][quad*8];
      bh[i] = *(const s8v*)&khi[wc*64 + i*16 + l16][quad*8];
      bl[i] = *(const s8v*)&klo[wc*64 + i*16 + l16][quad*8];
    }
#pragma unroll
    for (int i = 0; i < 4; ++i)
#pragma unroll
      for (int j = 0; j < 4; ++j) {
        acc[i][j] = __builtin_amdgcn_mfma_f32_16x16x32_bf16(ah[i], bh[j], acc[i][j], 0, 0, 0);
        acc[i][j] = __builtin_amdgcn_mfma_f32_16x16x32_bf16(al[i], bh[j], acc[i][j], 0, 0, 0);
        acc[i][j] = __builtin_amdgcn_mfma_f32_16x16x32_bf16(ah[i], bl[j], acc[i][j], 0, 0, 0);
      }
  }

  const float scale = 0.08838834764831845f;  // 1/sqrt(128)
  float csum[4] = {0.f, 0.f, 0.f, 0.f};
#pragma unroll
  for (int j = 0; j < 4; ++j) {
    int col = kb * 128 + wc * 64 + j * 16 + l16;
#pragma unroll
    for (int i = 0; i < 4; ++i) {
      int row0 = qb * 128 + wr * 64 + i * 16 + quad * 4;
#pragma unroll
      for (int r = 0; r < 4; ++r) {
        size_t off = ((size_t)b * TQ + row0 + r) * TK + col;
        float s = acc[i][j][r] * scale - 10000.0f * Msk[off];
        float p = __expf(s);              // exp(-1e4) underflows to 0 (masked)
        P[off] = p;
        csum[j] += p;
      }
    }
  }
#pragma unroll
  for (int j = 0; j < 4; ++j) {
    float v = csum[j];
    v += __shfl_xor(v, 16, 64);
    v += __shfl_xor(v, 32, 64);
    if (quad == 0)
      atomicAdd(&Z[b * TK + kb * 128 + wc * 64 + j * 16 + l16], v);
  }
}

// ---------------------------------------------------------------------------
// Kernel 2a: V[b,k,d] -> Vt_hi/Vt_lo[b,d,k] (bf16 split planes) via LDS tile.
// ---------------------------------------------------------------------------
__global__ __launch_bounds__(256) void vtrans_kernel(
    const float* __restrict__ V, unsigned short* __restrict__ Vthi,
    unsigned short* __restrict__ Vtlo)
{
  __shared__ float tile[64][65];
  const int k0 = blockIdx.x * 64, d0 = blockIdx.y * 64, b = blockIdx.z;
  const int tid = threadIdx.x;
#pragma unroll
  for (int i = 0; i < 4; ++i) {
    int idx = i * 256 + tid;
    int r = idx >> 4, c = (idx & 15) * 4;
    float4 v = *(const float4*)(V + ((size_t)b * TK + k0 + r) * DH + d0 + c);
    tile[r][c] = v.x; tile[r][c+1] = v.y; tile[r][c+2] = v.z; tile[r][c+3] = v.w;
  }
  __syncthreads();
  const int dr = tid >> 2, kq = (tid & 3) * 16;
  size_t base = ((size_t)b * DH + d0 + dr) * TK + k0 + kq;
  unsigned short hbuf[16], lbuf[16];
#pragma unroll
  for (int j = 0; j < 16; ++j) {
    float f = tile[kq + j][dr];
    unsigned short h = f2bf(f);
    hbuf[j] = h;
    lbuf[j] = f2bf(f - bf2f(h));
  }
#pragma unroll
  for (int m = 0; m < 4; ++m) {
    ushort4 hv = make_ushort4(hbuf[4*m], hbuf[4*m+1], hbuf[4*m+2], hbuf[4*m+3]);
    ushort4 lv = make_ushort4(lbuf[4*m], lbuf[4*m+1], lbuf[4*m+2], lbuf[4*m+3]);
    *(ushort4*)(Vthi + base + 4*m) = hv;
    *(ushort4*)(Vtlo + base + 4*m) = lv;
  }
}

// Kernel 2b: Rz = 1/Z
__global__ __launch_bounds__(256) void rz_kernel(const float* __restrict__ Z,
                                                 float* __restrict__ Rz) {
  int i = blockIdx.x * 256 + threadIdx.x;
  Rz[i] = 1.0f / Z[i];
}

// ---------------------------------------------------------------------------
// Kernel 3: attn = P * Rz[k] (written back in place), context = attn @ V.
// Computed as context^T = V^T @ attn^T so both MFMA operands are k-contiguous;
// epilogue transposes through LDS for coalesced context stores.
// ---------------------------------------------------------------------------
union __align__(16) SH3 {
  struct {
    unsigned short ahi[128][40];
    unsigned short alo[128][40];
    unsigned short vhi[128][40];
    unsigned short vlo[128][40];
  } s;
  float ctx[64][130];
};

__global__ __launch_bounds__(256) void av_kernel(
    float* __restrict__ Attn, const unsigned short* __restrict__ Vthi,
    const unsigned short* __restrict__ Vtlo, const float* __restrict__ Rz,
    float* __restrict__ Ctx)
{
  __shared__ SH3 sh;
  const int qb = blockIdx.x, b = blockIdx.y;
  const int tid = threadIdx.x;
  const int wave = tid >> 6, lane = tid & 63;
  const int wr = wave >> 1, wc = wave & 1;
  const int quad = lane >> 4, l16 = lane & 15;

  f4v acc[4][4];
#pragma unroll
  for (int i = 0; i < 4; ++i)
#pragma unroll
    for (int j = 0; j < 4; ++j)
      acc[i][j] = (f4v){0.f, 0.f, 0.f, 0.f};

  float* attnB = Attn + ((size_t)b * TQ + (size_t)qb * 128) * TK;
  const unsigned short* vhB = Vthi + (size_t)b * DH * TK;
  const unsigned short* vlB = Vtlo + (size_t)b * DH * TK;
  const float* rzB = Rz + (size_t)b * TK;

  for (int kc = 0; kc < TK; kc += 32) {
    __syncthreads();
#pragma unroll
    for (int i = 0; i < 4; ++i) {
      int idx = i * 256 + tid;
      int r = idx >> 3, c = (idx & 7) * 4;
      size_t off = (size_t)r * TK + kc + c;
      float4 pv = *(const float4*)(attnB + off);
      float4 rv = *(const float4*)(rzB + kc + c);
      float4 av;
      av.x = pv.x * rv.x; av.y = pv.y * rv.y;
      av.z = pv.z * rv.z; av.w = pv.w * rv.w;
      *(float4*)(attnB + off) = av;  // final normalized attn output
      unsigned short h;
      h = f2bf(av.x); sh.s.ahi[r][c+0] = h; sh.s.alo[r][c+0] = f2bf(av.x - bf2f(h));
      h = f2bf(av.y); sh.s.ahi[r][c+1] = h; sh.s.alo[r][c+1] = f2bf(av.y - bf2f(h));
      h = f2bf(av.z); sh.s.ahi[r][c+2] = h; sh.s.alo[r][c+2] = f2bf(av.z - bf2f(h));
      h = f2bf(av.w); sh.s.ahi[r][c+3] = h; sh.s.alo[r][c+3] = f2bf(av.w - bf2f(h));
    }
#pragma unroll
    for (int i = 0; i < 2; ++i) {
      int idx = i * 256 + tid;
      int d = idx >> 2, part = (idx & 3) * 8;
      *(uint4*)&sh.s.vhi[d][part] = *(const uint4*)(vhB + (size_t)d * TK + kc + part);
      *(uint4*)&sh.s.vlo[d][part] = *(const uint4*)(vlB + (size_t)d * TK + kc + part);
    }
    __syncthreads();

    s8v vh[4], vl[4], ah[4], al[4];
#pragma unroll
    for (int i = 0; i < 4; ++i) {
      vh[i] = *(const s8v*)&sh.s.vhi[wr*64 + i*16 + l16][quad*8];
      vl[i] = *(const s8v*)&sh.s.vlo[wr*64 + i*16 + l16][quad*8];
      ah[i] = *(const s8v*)&sh.s.ahi[wc*64 + i*16 + l16][quad*8];
      al[i] = *(const s8v*)&sh.s.alo[wc*64 + i*16 + l16][quad*8];
    }
#pragma unroll
    for (int i = 0; i < 4; ++i)
#pragma unroll
      for (int j = 0; j < 4; ++j) {
        acc[i][j] = __builtin_amdgcn_mfma_f32_16x16x32_bf16(vh[i], ah[j], acc[i][j], 0, 0, 0);
        acc[i][j] = __builtin_amdgcn_mfma_f32_16x16x32_bf16(vl[i], ah[j], acc[i][j], 0, 0, 0);
        acc[i][j] = __builtin_amdgcn_mfma_f32_16x16x32_bf16(vh[i], al[j], acc[i][j], 0, 0, 0);
      }
  }

  // Epilogue: acc holds context^T tiles (m=d, n=q). Transpose via LDS, two
  // passes of 64 q-rows each, coalesced float4 stores.
#pragma unroll
  for (int p = 0; p < 2; ++p) {
    __syncthreads();
    if (wc == p) {
#pragma unroll
      for (int i = 0; i < 4; ++i)
#pragma unroll
        for (int j = 0; j < 4; ++j)
#pragma unroll
          for (int r = 0; r < 4; ++r)
            sh.ctx[j*16 + l16][wr*64 + i*16 + quad*4 + r] = acc[i][j][r];
    }
    __syncthreads();
#pragma unroll
    for (int i = 0; i < 8; ++i) {
      int idx = i * 256 + tid;
      int r = idx >> 5, c = (idx & 31) * 4;
      float4 v;
      v.x = sh.ctx[r][c];   v.y = sh.ctx[r][c+1];
      v.z = sh.ctx[r][c+2]; v.w = sh.ctx[r][c+3];
      *(float4*)(Ctx + ((size_t)b * TQ + qb * 128 + p * 64 + r) * DH + c) = v;
    }
  }
}

// ---------------------------------------------------------------------------
extern "C" void kernel_launch(void* const* d_in, const int* in_sizes, int n_in,
                              void* d_out, int out_size, void* d_ws, size_t ws_size,
                              hipStream_t stream)
{
  const float* Q = (const float*)d_in[0];
  const float* K = (const float*)d_in[1];
  const float* V = (const float*)d_in[2];
  const float* M = (const float*)d_in[3];

  float* ctx  = (float*)d_out;
  float* attn = ctx + (size_t)BN * TQ * DH;   // outputs: context ++ attn

  // workspace layout: Z (128 KB) | @1MB: Vt_hi (8MB) | Vt_lo (8MB) | Rz (128KB)
  char* ws = (char*)d_ws;
  float* Z = (float*)ws;
  unsigned short* Vthi = (unsigned short*)(ws + (1 << 20));
  unsigned short* Vtlo = Vthi + (size_t)BN * DH * TK;
  float* Rz = (float*)(ws + (1 << 20) + (size_t)BN * DH * TK * 4);

  hipMemsetAsync(Z, 0, (size_t)BN * TK * sizeof(float), stream);
  vtrans_kernel<<<dim3(TK/64, DH/64, BN), 256, 0, stream>>>(V, Vthi, Vtlo);
  qk_exp_kernel<<<dim3(TK/128, TQ/128, BN), 256, 0, stream>>>(Q, K, M, attn, Z);
  rz_kernel<<<dim3((BN*TK)/256), 256, 0, stream>>>(Z, Rz);
  av_kernel<<<dim3(TQ/128, BN), 256, 0, stream>>>(attn, Vthi, Vtlo, Rz, ctx);
}